// Round 4
// baseline (798.179 us; speedup 1.0000x reference)
//
#include <hip/hip_runtime.h>
#include <cstdint>

#define BATCH 128
#define NODES 1023
#define LEAVES 512
#define IN_DIM 300
#define MEM 300
#define NP 320              // padded per-set N (and per-child K)
#define OUT_HALF (BATCH*MEM)

typedef __bf16   bf16x8 __attribute__((ext_vector_type(8)));
typedef short    s16x8  __attribute__((ext_vector_type(8)));
typedef short    s16x4  __attribute__((ext_vector_type(4)));
typedef float    f32x4  __attribute__((ext_vector_type(4)));
typedef _Float16 half_t;

__device__ __forceinline__ short f2bf(float f) {
    unsigned u = __float_as_uint(f);
    u += 0x7fff + ((u >> 16) & 1);
    return (short)(u >> 16);
}
__device__ __forceinline__ float sigf(float x)  { return 1.0f / (1.0f + __expf(-x)); }
__device__ __forceinline__ float tanhf_(float x){ return 1.0f - 2.0f / (1.0f + __expf(2.0f * x)); }

__device__ __forceinline__ f32x4 mfma16(s16x8 a, s16x8 b, f32x4 c) {
    return __builtin_amdgcn_mfma_f32_16x16x32_bf16(
        __builtin_bit_cast(bf16x8, a), __builtin_bit_cast(bf16x8, b), c, 0, 0, 0);
}

// async 16B/lane global->LDS: lds dst = wave-uniform base + lane*16
__device__ __forceinline__ void dma16(const short* src, short* ldsBase) {
    __builtin_amdgcn_global_load_lds(
        (const __attribute__((address_space(1))) unsigned int*)src,
        (__attribute__((address_space(3))) unsigned int*)ldsBase,
        16, 0, 0);
}

// ---------- weight packing: B-fragment order ----------
// frag-block (kb,s,nb): 64 lanes x 8 bf16; lane l holds B[k=kb*32+(l>>4)*8+j][n=nb*16+(l&15)]
__global__ __launch_bounds__(256) void pack_node_w(
    const float* __restrict__ Wiouh, const float* __restrict__ Wfh, short* __restrict__ Wpk)
{
    int gid = blockIdx.x * 256 + threadIdx.x;           // 2000 frags * 64 lanes
    if (gid >= 2000 * 64) return;
    int fb = gid >> 6, l = gid & 63;
    int kb = fb / 100, rem = fb % 100, s = rem / 20, nb = rem % 20;
    int n = nb * 16 + (l & 15);
    int kbase = kb * 32 + (l >> 4) * 8;                 // k' in [0,640)
    short v[8];
#pragma unroll
    for (int j = 0; j < 8; ++j) {
        int kp = kbase + j;
        int side = kp >= NP;
        int kk = kp - side * NP;
        float f = 0.0f;
        if (kk < MEM && n < MEM) {
            int k = side * MEM + kk;
            f = (s < 3) ? Wiouh[(size_t)k * 900 + s * 300 + n]
                        : Wfh[(size_t)k * 600 + (s - 3) * 300 + n];
        }
        v[j] = f2bf(f);
    }
    *(s16x8*)&Wpk[(size_t)gid * 8] = *(s16x8*)v;
}

__global__ __launch_bounds__(256) void pack_leaf_w(
    const float* __restrict__ Wfioux, short* __restrict__ Wpk)
{
    int gid = blockIdx.x * 256 + threadIdx.x;           // 600 frags * 64 lanes
    if (gid >= 600 * 64) return;
    int fb = gid >> 6, l = gid & 63;
    int kb = fb / 60, rem = fb % 60, s = rem / 20, nb = rem % 20;
    int n = nb * 16 + (l & 15);
    int kbase = kb * 32 + (l >> 4) * 8;                 // k' in [0,320)
    short v[8];
#pragma unroll
    for (int j = 0; j < 8; ++j) {
        int kp = kbase + j;
        float f = 0.0f;
        if (kp < IN_DIM && n < MEM)
            f = Wfioux[(size_t)kp * 1200 + (s + 1) * 300 + n];
        v[j] = f2bf(f);
    }
    *(s16x8*)&Wpk[(size_t)gid * 8] = *(s16x8*)v;
}

// ---------- leaf-input packing: X[leaf][b][kp] bf16, kp padded to 320 ----------
__global__ __launch_bounds__(256) void pack_x(
    const float* __restrict__ inputs, short* __restrict__ X)
{
    int gid = blockIdx.x * 256 + threadIdx.x;           // 512*128*80 quads
    if (gid >= LEAVES * BATCH * (NP / 4)) return;
    int q = gid % (NP / 4);
    int rb = gid / (NP / 4);
    int b = rb % BATCH, leaf = rb / BATCH;
    short v[4] = {0, 0, 0, 0};
    if (q < IN_DIM / 4) {
        f32x4 f = *(const f32x4*)&inputs[((size_t)b * NODES + leaf) * IN_DIM + q * 4];
        v[0] = f2bf(f[0]); v[1] = f2bf(f[1]); v[2] = f2bf(f[2]); v[3] = f2bf(f[3]);
    }
    *(s16x4*)&X[(size_t)gid * 4] = *(s16x4*)v;
}

// ---------- leaf GEMM+gates: block = 1 leaf x 64-col group ----------
// Wave tile = 2M x 2N: wave (mw,nw) owns 64 rows x 2-of-4 col frags per set.
// Halves per-step LDS B-reads vs 4xM split (each wave: 6 B-reads, 4 A-loads,
// 24 MFMAs). T3+T4 pipeline: 4-buf LDS ring depth-3 for B, 2-slot A ring
// depth-1 (A hits L2 post-swizzle), counted vmcnt before raw s_barrier.
// XCD swizzle: all 5 col-groups of a leaf on one XCD.
__global__ __launch_bounds__(256, 3) void leaf_mfma(
    const short* __restrict__ X, const short* __restrict__ Wpk,
    const float* __restrict__ b_fioux, half_t* __restrict__ C, short* __restrict__ H)
{
    __shared__ short Bs[4][12 * 512];                   // 4 ring bufs x 12 frags x 1KB
    const int t = threadIdx.x;
    const int l = t & 63, w = t >> 6;
    const int lane16 = l & 15, quad = l >> 4;
    const int mw = w >> 1, nw = w & 1;                  // 2M x 2N wave grid

    // bid = (leaf%8) + 8*(y + 5*(leaf/8))  ->  decode:
    const int bid = blockIdx.x;
    const int xcd = bid & 7, tt = bid >> 3;
    const int y = tt % 5;                               // 64-col group 0..4
    const int leaf = (tt / 5) * 8 + xcd;

    const short* Xb = X + (size_t)leaf * BATCH * NP;

    f32x4 acc[3][2][4];                                 // [set][col-frag-half][row-frag]
#pragma unroll
    for (int s = 0; s < 3; ++s)
#pragma unroll
        for (int fh = 0; fh < 2; ++fh)
#pragma unroll
            for (int rh = 0; rh < 4; ++rh) acc[s][fh][rh] = (f32x4)(0.0f);

    s16x8 A[2][4];                                      // A ring: 2 slots x 4 row-frags

#define L_STAGE(KB, BUF) do {                                                    \
    _Pragma("unroll")                                                            \
    for (int fl = w; fl < 12; fl += 4) {                                         \
        int s_ = fl >> 2, f_ = fl & 3;                                           \
        const short* src_ = Wpk +                                                \
            ((size_t)(((KB) * 3 + s_) * 20 + y * 4 + f_) * 64 + l) * 8;          \
        dma16(src_, &Bs[BUF][fl * 512]);                                         \
    } } while (0)

#define L_ALOAD(KB, SLOT) do {                                                   \
    const int koff_ = (KB) * 32 + quad * 8;                                      \
    _Pragma("unroll")                                                            \
    for (int rh_ = 0; rh_ < 4; ++rh_)                                            \
        A[SLOT][rh_] = *(const s16x8*)(Xb +                                      \
            (size_t)(mw * 64 + rh_ * 16 + lane16) * NP + koff_);                 \
} while (0)

    // prologue: A0 first (oldest), then B0,B1,B2
    L_ALOAD(0, 0);
    L_STAGE(0, 0); L_STAGE(1, 1); L_STAGE(2, 2);

// per step ST: wait (keeps newest B-stage in flight) -> barrier -> aload A(ST+1)
// -> stage B(ST+3) -> MFMAs on A[ST&1], Bs[ST&3]. Ring distance 3 on B makes
// the WAR safe (readers of (ST+3)&3 finished before this barrier).
#define L_STEP(ST, WAITN) do {                                                   \
    asm volatile("s_waitcnt vmcnt(" #WAITN ")" ::: "memory");                    \
    __builtin_amdgcn_s_barrier();                                                \
    asm volatile("" ::: "memory");                                               \
    if ((ST) + 1 < 10) L_ALOAD((ST) + 1, ((ST) + 1) & 1);                        \
    if ((ST) + 3 < 10) L_STAGE((ST) + 3, ((ST) + 3) & 3);                        \
    _Pragma("unroll")                                                            \
    for (int s_ = 0; s_ < 3; ++s_) {                                             \
        _Pragma("unroll")                                                        \
        for (int fh_ = 0; fh_ < 2; ++fh_) {                                      \
            s16x8 b_ = *(const s16x8*)                                           \
                &Bs[(ST) & 3][(s_ * 4 + nw * 2 + fh_) * 512 + l * 8];            \
            _Pragma("unroll")                                                    \
            for (int rh_ = 0; rh_ < 4; ++rh_)                                    \
                acc[s_][fh_][rh_] = mfma16(A[(ST) & 1][rh_], b_, acc[s_][fh_][rh_]); \
        }                                                                        \
    } } while (0)

    L_STEP(0, 6); L_STEP(1, 3); L_STEP(2, 3); L_STEP(3, 3); L_STEP(4, 3);
    L_STEP(5, 3); L_STEP(6, 3); L_STEP(7, 3); L_STEP(8, 0); L_STEP(9, 0);

#undef L_STEP
#undef L_ALOAD
#undef L_STAGE

#pragma unroll
    for (int fh = 0; fh < 2; ++fh) {
        const int col = y * 64 + (nw * 2 + fh) * 16 + lane16;
        const bool valid = col < MEM;
        float bi = 0, bo = 0, bu = 0;
        if (valid) { bi = b_fioux[300 + col]; bo = b_fioux[600 + col]; bu = b_fioux[900 + col]; }
#pragma unroll
        for (int rh = 0; rh < 4; ++rh)
#pragma unroll
            for (int r = 0; r < 4; ++r) {
                int b = mw * 64 + rh * 16 + quad * 4 + r;
                size_t hIdx = ((size_t)leaf * BATCH + b) * NP + col;
                if (valid) {
                    float ig = sigf(acc[0][fh][rh][r] + bi);
                    float og = sigf(acc[1][fh][rh][r] + bo);
                    float ug = tanhf_(acc[2][fh][rh][r] + bu);
                    float c = ig * ug;
                    float h = og * tanhf_(c);
                    C[((size_t)leaf * BATCH + b) * MEM + col] = (half_t)c;
                    H[hIdx] = f2bf(h);
                } else {
                    H[hIdx] = 0;
                }
            }
    }
}

// ---------- internal node GEMM+gates: block = 1 node x 32-col group ----------
// Wave tile = 2M x 2N: wave (mw,nw) owns 64 rows x 1-of-2 col frags per set
// (5 B-reads, 4 A-loads, 20 MFMAs per step). K-step 32, 20 steps over K'=640.
// Staging padded to 12 frags/step (slots 10,11 duplicate 0,1) so every wave
// issues exactly 3 dma16 + 1 aload(4 ops) per step -> uniform vmcnt constants.
// XCD swizzle (when #nodes % 8 == 0): all 10 col-groups of a node on one XCD.
__global__ __launch_bounds__(256, 3) void node_mfma(
    const short* __restrict__ Wpk, const float* __restrict__ b_fioux,
    const int* __restrict__ left_idx, const int* __restrict__ right_idx,
    half_t* __restrict__ C, short* __restrict__ H,
    int level_start, int level_size, float* __restrict__ out)
{
    __shared__ short Bs[4][12 * 512];                   // 4 ring bufs x 12KB
    const int t = threadIdx.x;
    const int l = t & 63, w = t >> 6;
    const int lane16 = l & 15, quad = l >> 4;
    const int mw = w >> 1, nw = w & 1;                  // 2M x 2N wave grid

    const int bid = blockIdx.x;
    int nidx, y;
    if ((level_size & 7) == 0) {
        // bid = (n%8) + 8*(y + 10*(n/8))
        const int xcd = bid & 7, tt = bid >> 3;
        y = tt % 10;
        nidx = (tt / 10) * 8 + xcd;
    } else {
        nidx = bid % level_size;
        y = bid / level_size;
    }
    const int node = level_start + nidx;

    const int li = left_idx[node], ri = right_idx[node];
    const short* HL = H + (size_t)li * BATCH * NP;
    const short* HR = H + (size_t)ri * BATCH * NP;

    f32x4 acc[5][4];                                    // [set][row-frag]
#pragma unroll
    for (int s = 0; s < 5; ++s)
#pragma unroll
        for (int rh = 0; rh < 4; ++rh) acc[s][rh] = (f32x4)(0.0f);

    s16x8 A[2][4];                                      // A ring: 2 slots x 4 row-frags

#define N_STAGE(KB, BUF) do {                                                    \
    _Pragma("unroll")                                                            \
    for (int fl = w; fl < 12; fl += 4) {                                         \
        int rfl_ = (fl < 10) ? fl : fl - 10;            /* slots 10,11: dup */   \
        int s_ = rfl_ >> 1, f_ = rfl_ & 1;                                       \
        const short* src_ = Wpk +                                                \
            ((size_t)(((KB) * 5 + s_) * 20 + y * 2 + f_) * 64 + l) * 8;          \
        dma16(src_, &Bs[BUF][fl * 512]);                                         \
    } } while (0)

#define N_ALOAD(KB, SLOT) do {                                                   \
    const short* Hb_ = (((KB) >= 10) ? HR : HL) +                                \
                       ((KB) - (((KB) >= 10) ? 10 : 0)) * 32 + quad * 8;         \
    _Pragma("unroll")                                                            \
    for (int rh_ = 0; rh_ < 4; ++rh_)                                            \
        A[SLOT][rh_] = *(const s16x8*)(Hb_ +                                     \
            (size_t)(mw * 64 + rh_ * 16 + lane16) * NP);                         \
} while (0)

    N_ALOAD(0, 0);
    N_STAGE(0, 0); N_STAGE(1, 1); N_STAGE(2, 2);

#define N_STEP(ST, WAITN) do {                                                   \
    asm volatile("s_waitcnt vmcnt(" #WAITN ")" ::: "memory");                    \
    __builtin_amdgcn_s_barrier();                                                \
    asm volatile("" ::: "memory");                                               \
    if ((ST) + 1 < 20) N_ALOAD((ST) + 1, ((ST) + 1) & 1);                        \
    if ((ST) + 3 < 20) N_STAGE((ST) + 3, ((ST) + 3) & 3);                        \
    _Pragma("unroll")                                                            \
    for (int s_ = 0; s_ < 5; ++s_) {                                             \
        s16x8 b_ = *(const s16x8*)                                               \
            &Bs[(ST) & 3][(s_ * 2 + nw) * 512 + l * 8];                          \
        _Pragma("unroll")                                                        \
        for (int rh_ = 0; rh_ < 4; ++rh_)                                        \
            acc[s_][rh_] = mfma16(A[(ST) & 1][rh_], b_, acc[s_][rh_]);           \
    } } while (0)

    N_STEP(0, 6);   N_STEP(1, 3);   N_STEP(2, 3);   N_STEP(3, 3);   N_STEP(4, 3);
    N_STEP(5, 3);   N_STEP(6, 3);   N_STEP(7, 3);   N_STEP(8, 3);   N_STEP(9, 3);
    N_STEP(10, 3);  N_STEP(11, 3);  N_STEP(12, 3);  N_STEP(13, 3);  N_STEP(14, 3);
    N_STEP(15, 3);  N_STEP(16, 3);  N_STEP(17, 3);  N_STEP(18, 0);  N_STEP(19, 0);

#undef N_STEP
#undef N_ALOAD
#undef N_STAGE

    {
        const int col = y * 32 + nw * 16 + lane16;
        const bool valid = col < MEM;
        float bff = 0, bi = 0, bo = 0, bu = 0;
        if (valid) {
            bff = b_fioux[col]; bi = b_fioux[300 + col];
            bo = b_fioux[600 + col]; bu = b_fioux[900 + col];
        }
#pragma unroll
        for (int rh = 0; rh < 4; ++rh)
#pragma unroll
            for (int r = 0; r < 4; ++r) {
                int row = mw * 64 + rh * 16 + quad * 4 + r;
                size_t hIdx = ((size_t)node * BATCH + row) * NP + col;
                if (valid) {
                    float cl = (float)C[((size_t)li * BATCH + row) * MEM + col];
                    float cr = (float)C[((size_t)ri * BATCH + row) * MEM + col];
                    float ig = sigf(acc[0][rh][r] + bi);
                    float og = sigf(acc[1][rh][r] + bo);
                    float ug = tanhf_(acc[2][rh][r] + bu);
                    float fl = sigf(acc[3][rh][r] + bff);
                    float fr = sigf(acc[4][rh][r] + bff);
                    float c = ig * ug + fl * cl + fr * cr;
                    float h = og * tanhf_(c);
                    C[((size_t)node * BATCH + row) * MEM + col] = (half_t)c;
                    H[hIdx] = f2bf(h);
                    if (out) {
                        out[row * MEM + col] = c;
                        out[OUT_HALF + row * MEM + col] = h;
                    }
                } else {
                    H[hIdx] = 0;
                }
            }
    }
}

extern "C" void kernel_launch(void* const* d_in, const int* in_sizes, int n_in,
                              void* d_out, int out_size, void* d_ws, size_t ws_size,
                              hipStream_t stream) {
    const float* inputs  = (const float*)d_in[0];
    const float* Wfioux  = (const float*)d_in[1];
    const float* b_fioux = (const float*)d_in[2];
    const float* Wiouh   = (const float*)d_in[3];
    const float* Wfh     = (const float*)d_in[4];
    const int*   left_idx  = (const int*)d_in[5];
    const int*   right_idx = (const int*)d_in[6];

    half_t* C   = (half_t*)d_ws;                              // [1023][128][300] fp16
    short*  H   = (short*)(C + (size_t)NODES * BATCH * MEM);  // [1023][128][320] bf16
    short* WpkN = H + (size_t)NODES * BATCH * NP;             // 2000 frag-blocks
    short* WpkL = WpkN + (size_t)2000 * 512;                  // 600 frag-blocks
    short* X    = WpkL + (size_t)600 * 512;                   // [512][128][320] bf16
    float* out  = (float*)d_out;

    pack_x<<<(LEAVES * BATCH * (NP / 4) + 255) / 256, 256, 0, stream>>>(inputs, X);
    pack_leaf_w<<<150, 256, 0, stream>>>(Wfioux, WpkL);
    pack_node_w<<<500, 256, 0, stream>>>(Wiouh, Wfh, WpkN);

    leaf_mfma<<<LEAVES * 5, 256, 0, stream>>>(X, WpkL, b_fioux, C, H);

    static const int starts[9] = {512, 768, 896, 960, 992, 1008, 1016, 1020, 1022};
    static const int sizes [9] = {256, 128,  64,  32,  16,    8,    4,    2,    1};
    for (int lvl = 0; lvl < 9; ++lvl) {
        bool root = (lvl == 8);
        node_mfma<<<sizes[lvl] * 10, 256, 0, stream>>>(
            WpkN, b_fioux, left_idx, right_idx, C, H, starts[lvl], sizes[lvl],
            root ? out : nullptr);
    }
}

// Round 5
// 621.822 us; speedup vs baseline: 1.2836x; 1.2836x over previous
//
#include <hip/hip_runtime.h>
#include <cstdint>

#define BATCH 128
#define NODES 1023
#define LEAVES 512
#define IN_DIM 300
#define MEM 300
#define NP 320              // padded per-set N (and per-child K)
#define OUT_HALF (BATCH*MEM)

typedef __bf16   bf16x8 __attribute__((ext_vector_type(8)));
typedef short    s16x8  __attribute__((ext_vector_type(8)));
typedef short    s16x4  __attribute__((ext_vector_type(4)));
typedef float    f32x4  __attribute__((ext_vector_type(4)));
typedef _Float16 half_t;

__device__ __forceinline__ short f2bf(float f) {
    unsigned u = __float_as_uint(f);
    u += 0x7fff + ((u >> 16) & 1);
    return (short)(u >> 16);
}
__device__ __forceinline__ float sigf(float x)  { return 1.0f / (1.0f + __expf(-x)); }
__device__ __forceinline__ float tanhf_(float x){ return 1.0f - 2.0f / (1.0f + __expf(2.0f * x)); }

__device__ __forceinline__ f32x4 mfma16(s16x8 a, s16x8 b, f32x4 c) {
    return __builtin_amdgcn_mfma_f32_16x16x32_bf16(
        __builtin_bit_cast(bf16x8, a), __builtin_bit_cast(bf16x8, b), c, 0, 0, 0);
}

// async 16B/lane global->LDS: lds dst = wave-uniform base + lane*16
__device__ __forceinline__ void dma16(const short* src, short* ldsBase) {
    __builtin_amdgcn_global_load_lds(
        (const __attribute__((address_space(1))) unsigned int*)src,
        (__attribute__((address_space(3))) unsigned int*)ldsBase,
        16, 0, 0);
}

// ---------- weight packing: B-fragment order ----------
// frag-block (kb,s,nb): 64 lanes x 8 bf16; lane l holds B[k=kb*32+(l>>4)*8+j][n=nb*16+(l&15)]
__global__ __launch_bounds__(256) void pack_node_w(
    const float* __restrict__ Wiouh, const float* __restrict__ Wfh, short* __restrict__ Wpk)
{
    int gid = blockIdx.x * 256 + threadIdx.x;           // 2000 frags * 64 lanes
    if (gid >= 2000 * 64) return;
    int fb = gid >> 6, l = gid & 63;
    int kb = fb / 100, rem = fb % 100, s = rem / 20, nb = rem % 20;
    int n = nb * 16 + (l & 15);
    int kbase = kb * 32 + (l >> 4) * 8;                 // k' in [0,640)
    short v[8];
#pragma unroll
    for (int j = 0; j < 8; ++j) {
        int kp = kbase + j;
        int side = kp >= NP;
        int kk = kp - side * NP;
        float f = 0.0f;
        if (kk < MEM && n < MEM) {
            int k = side * MEM + kk;
            f = (s < 3) ? Wiouh[(size_t)k * 900 + s * 300 + n]
                        : Wfh[(size_t)k * 600 + (s - 3) * 300 + n];
        }
        v[j] = f2bf(f);
    }
    *(s16x8*)&Wpk[(size_t)gid * 8] = *(s16x8*)v;
}

__global__ __launch_bounds__(256) void pack_leaf_w(
    const float* __restrict__ Wfioux, short* __restrict__ Wpk)
{
    int gid = blockIdx.x * 256 + threadIdx.x;           // 600 frags * 64 lanes
    if (gid >= 600 * 64) return;
    int fb = gid >> 6, l = gid & 63;
    int kb = fb / 60, rem = fb % 60, s = rem / 20, nb = rem % 20;
    int n = nb * 16 + (l & 15);
    int kbase = kb * 32 + (l >> 4) * 8;                 // k' in [0,320)
    short v[8];
#pragma unroll
    for (int j = 0; j < 8; ++j) {
        int kp = kbase + j;
        float f = 0.0f;
        if (kp < IN_DIM && n < MEM)
            f = Wfioux[(size_t)kp * 1200 + (s + 1) * 300 + n];
        v[j] = f2bf(f);
    }
    *(s16x8*)&Wpk[(size_t)gid * 8] = *(s16x8*)v;
}

// ---------- leaf-input packing: X[leaf][b][kp] bf16, kp padded to 320 ----------
__global__ __launch_bounds__(256) void pack_x(
    const float* __restrict__ inputs, short* __restrict__ X)
{
    int gid = blockIdx.x * 256 + threadIdx.x;           // 512*128*80 quads
    if (gid >= LEAVES * BATCH * (NP / 4)) return;
    int q = gid % (NP / 4);
    int rb = gid / (NP / 4);
    int b = rb % BATCH, leaf = rb / BATCH;
    short v[4] = {0, 0, 0, 0};
    if (q < IN_DIM / 4) {
        f32x4 f = *(const f32x4*)&inputs[((size_t)b * NODES + leaf) * IN_DIM + q * 4];
        v[0] = f2bf(f[0]); v[1] = f2bf(f[1]); v[2] = f2bf(f[2]); v[3] = f2bf(f[3]);
    }
    *(s16x4*)&X[(size_t)gid * 4] = *(s16x4*)v;
}

// ---------- leaf GEMM+gates: block = 1 leaf x 64-col group ----------
// (round-3 version, verbatim: 4xM wave split, 4-buf ring depth-3, counted
// vmcnt(10) steady; XCD swizzle groups a leaf's 5 col-groups on one XCD.)
__global__ __launch_bounds__(256, 3) void leaf_mfma(
    const short* __restrict__ X, const short* __restrict__ Wpk,
    const float* __restrict__ b_fioux, half_t* __restrict__ C, short* __restrict__ H)
{
    __shared__ short Bs[4][12 * 512];                   // 4 ring bufs x 12 frags x 1KB
    const int t = threadIdx.x;
    const int l = t & 63, w = t >> 6;                   // 4 waves, w = row-group
    const int lane16 = l & 15, quad = l >> 4;

    // bid = (leaf%8) + 8*(y + 5*(leaf/8))  ->  decode:
    const int bid = blockIdx.x;
    const int xcd = bid & 7, tt = bid >> 3;
    const int y = tt % 5;                               // 64-col group 0..4
    const int leaf = (tt / 5) * 8 + xcd;

    const short* Xb = X + (size_t)leaf * BATCH * NP;

    f32x4 acc[3][4][2];                                 // [set][frag][row-half]
#pragma unroll
    for (int s = 0; s < 3; ++s)
#pragma unroll
        for (int f = 0; f < 4; ++f)
#pragma unroll
            for (int mi = 0; mi < 2; ++mi) acc[s][f][mi] = (f32x4)(0.0f);

    s16x8 A[4][2];                                      // A-fragment ring (static idx only)

#define L_STAGE(KB, BUF) do {                                                    \
    _Pragma("unroll")                                                            \
    for (int fl = w; fl < 12; fl += 4) {                                         \
        int s_ = fl >> 2, f_ = fl & 3;                                           \
        const short* src_ = Wpk +                                                \
            ((size_t)(((KB) * 3 + s_) * 20 + y * 4 + f_) * 64 + l) * 8;          \
        dma16(src_, &Bs[BUF][fl * 512]);                                         \
    } } while (0)

#define L_ALOAD(KB, SLOT) do {                                                   \
    const int koff_ = (KB) * 32 + quad * 8;                                      \
    A[SLOT][0] = *(const s16x8*)(Xb + (size_t)(w * 32 + lane16) * NP + koff_);   \
    A[SLOT][1] = *(const s16x8*)(Xb + (size_t)(w * 32 + 16 + lane16) * NP + koff_); \
} while (0)

    // prologue: issue steps 0,1,2 (15 vmem ops per wave in flight)
    L_STAGE(0, 0); L_ALOAD(0, 0);
    L_STAGE(1, 1); L_ALOAD(1, 1);
    L_STAGE(2, 2); L_ALOAD(2, 2);

// waitcnt BEFORE barrier: guarantees every wave's step-ST stage is complete when
// any wave crosses. issue AFTER barrier: ring distance 3 makes the WAR on buffer
// (ST+3)&3 == (ST-1)&3 safe (its readers finished before this barrier).
#define L_STEP(ST, WAITN) do {                                                   \
    asm volatile("s_waitcnt vmcnt(" #WAITN ")" ::: "memory");                    \
    __builtin_amdgcn_s_barrier();                                                \
    asm volatile("" ::: "memory");                                               \
    if ((ST) + 3 < 10) { L_STAGE((ST) + 3, ((ST) + 3) & 3);                      \
                         L_ALOAD((ST) + 3, ((ST) + 3) & 3); }                    \
    _Pragma("unroll")                                                            \
    for (int s_ = 0; s_ < 3; ++s_) {                                             \
        _Pragma("unroll")                                                        \
        for (int f_ = 0; f_ < 4; ++f_) {                                         \
            s16x8 b_ = *(const s16x8*)&Bs[(ST) & 3][(s_ * 4 + f_) * 512 + l * 8];\
            acc[s_][f_][0] = mfma16(A[(ST) & 3][0], b_, acc[s_][f_][0]);         \
            acc[s_][f_][1] = mfma16(A[(ST) & 3][1], b_, acc[s_][f_][1]);         \
        }                                                                        \
    } } while (0)

    L_STEP(0, 10); L_STEP(1, 10); L_STEP(2, 10); L_STEP(3, 10); L_STEP(4, 10);
    L_STEP(5, 10); L_STEP(6, 10); L_STEP(7, 10); L_STEP(8, 5);  L_STEP(9, 0);

#undef L_STEP
#undef L_ALOAD
#undef L_STAGE

#pragma unroll
    for (int f = 0; f < 4; ++f) {
        const int col = y * 64 + f * 16 + lane16;
        const bool valid = col < MEM;
        float bi = 0, bo = 0, bu = 0;
        if (valid) { bi = b_fioux[300 + col]; bo = b_fioux[600 + col]; bu = b_fioux[900 + col]; }
#pragma unroll
        for (int mi = 0; mi < 2; ++mi)
#pragma unroll
            for (int r = 0; r < 4; ++r) {
                int b = w * 32 + mi * 16 + quad * 4 + r;
                size_t hIdx = ((size_t)leaf * BATCH + b) * NP + col;
                if (valid) {
                    float ig = sigf(acc[0][f][mi][r] + bi);
                    float og = sigf(acc[1][f][mi][r] + bo);
                    float ug = tanhf_(acc[2][f][mi][r] + bu);
                    float c = ig * ug;
                    float h = og * tanhf_(c);
                    C[((size_t)leaf * BATCH + b) * MEM + col] = (half_t)c;
                    H[hIdx] = f2bf(h);
                } else {
                    H[hIdx] = 0;
                }
            }
    }
}

// ---------- internal node GEMM+gates: block = 1 node x 32-col group ----------
// K-step 64 (10 steps over K'=640; round-1-verified geometry: 20 frags/step,
// exactly 5 dma/wave, acc[5][2][2], 40 MFMAs/wave/step) + deep pipeline:
// 4-buffer x 20KB LDS ring, depth-3 issue for B-stage AND A-register ring,
// steady s_waitcnt vmcnt(18) = 2 full K64-steps in flight past every barrier
// (4x the round-3 window in time, half the sync points). 80KB LDS -> 2
// blocks/CU; bounds(256,2) gives the register budget for A[4][2][2].
// XCD swizzle (when #nodes % 8 == 0): all 10 col-groups of a node on one XCD.
__global__ __launch_bounds__(256, 2) void node_mfma(
    const short* __restrict__ Wpk, const float* __restrict__ b_fioux,
    const int* __restrict__ left_idx, const int* __restrict__ right_idx,
    half_t* __restrict__ C, short* __restrict__ H,
    int level_start, int level_size, float* __restrict__ out)
{
    __shared__ short Bs[4][20 * 512];                   // 4 ring bufs x 20KB = 80KB
    const int t = threadIdx.x;
    const int l = t & 63, w = t >> 6;                   // 4 waves, w = row-group
    const int lane16 = l & 15, quad = l >> 4;

    const int bid = blockIdx.x;
    int nidx, y;
    if ((level_size & 7) == 0) {
        // bid = (n%8) + 8*(y + 10*(n/8))
        const int xcd = bid & 7, tt = bid >> 3;
        y = tt % 10;
        nidx = (tt / 10) * 8 + xcd;
    } else {
        nidx = bid % level_size;
        y = bid / level_size;
    }
    const int node = level_start + nidx;

    const int li = left_idx[node], ri = right_idx[node];
    const short* HL = H + (size_t)li * BATCH * NP;
    const short* HR = H + (size_t)ri * BATCH * NP;

    f32x4 acc[5][2][2];                                 // [set][frag][row-half]
#pragma unroll
    for (int s = 0; s < 5; ++s)
#pragma unroll
        for (int f = 0; f < 2; ++f)
#pragma unroll
            for (int mi = 0; mi < 2; ++mi) acc[s][f][mi] = (f32x4)(0.0f);

    s16x8 A[4][2][2];                                   // ring: 4 slots x ksub x row-half

// frag layout in LDS buffer: fl = ksub*10 + s*2 + f  (ksub = which 32-K half)
#define N_STAGE(ST, BUF) do {                                                    \
    _Pragma("unroll")                                                            \
    for (int fl = w; fl < 20; fl += 4) {               /* 5 frags per wave */    \
        int ksub_ = fl / 10, rem_ = fl - ksub_ * 10;                             \
        int s_ = rem_ >> 1, f_ = rem_ & 1;                                       \
        int kb32_ = (ST) * 2 + ksub_;                                            \
        const short* src_ = Wpk +                                                \
            ((size_t)((kb32_ * 5 + s_) * 20 + y * 2 + f_) * 64 + l) * 8;         \
        dma16(src_, &Bs[BUF][fl * 512]);                                         \
    } } while (0)

#define N_ALOAD(ST, SLOT) do {                                                   \
    const int side_ = (ST) >= 5;                                                 \
    const short* Hb_ = (side_ ? HR : HL) + ((ST) - side_ * 5) * 64 + quad * 8;   \
    _Pragma("unroll")                                                            \
    for (int ksub_ = 0; ksub_ < 2; ++ksub_) {                                    \
        A[SLOT][ksub_][0] = *(const s16x8*)(Hb_ +                                \
            (size_t)(w * 32 + lane16) * NP + ksub_ * 32);                        \
        A[SLOT][ksub_][1] = *(const s16x8*)(Hb_ +                                \
            (size_t)(w * 32 + 16 + lane16) * NP + ksub_ * 32);                   \
    } } while (0)

    // prologue: issue steps 0,1,2 (27 vmem ops per wave in flight)
    N_STAGE(0, 0); N_ALOAD(0, 0);
    N_STAGE(1, 1); N_ALOAD(1, 1);
    N_STAGE(2, 2); N_ALOAD(2, 2);

// per step: 5 dma + 4 A-loads = 9 vmem ops/wave. wait vmcnt(18) keeps the two
// newest steps in flight; barrier; issue step ST+3 (ring distance 3 => WAR on
// buffer (ST-1)&3 is safe: its readers finished before this barrier); 40 MFMAs.
#define N_STEP(ST, WAITN) do {                                                   \
    asm volatile("s_waitcnt vmcnt(" #WAITN ")" ::: "memory");                    \
    __builtin_amdgcn_s_barrier();                                                \
    asm volatile("" ::: "memory");                                               \
    if ((ST) + 3 < 10) { N_STAGE((ST) + 3, ((ST) + 3) & 3);                      \
                         N_ALOAD((ST) + 3, ((ST) + 3) & 3); }                    \
    _Pragma("unroll")                                                            \
    for (int ks_ = 0; ks_ < 2; ++ks_) {                                          \
        _Pragma("unroll")                                                        \
        for (int s_ = 0; s_ < 5; ++s_) {                                         \
            _Pragma("unroll")                                                    \
            for (int f_ = 0; f_ < 2; ++f_) {                                     \
                s16x8 b_ = *(const s16x8*)                                       \
                    &Bs[(ST) & 3][(ks_ * 10 + s_ * 2 + f_) * 512 + l * 8];       \
                acc[s_][f_][0] = mfma16(A[(ST) & 3][ks_][0], b_, acc[s_][f_][0]);\
                acc[s_][f_][1] = mfma16(A[(ST) & 3][ks_][1], b_, acc[s_][f_][1]);\
            }                                                                    \
        }                                                                        \
    } } while (0)

    N_STEP(0, 18); N_STEP(1, 18); N_STEP(2, 18); N_STEP(3, 18); N_STEP(4, 18);
    N_STEP(5, 18); N_STEP(6, 18); N_STEP(7, 18); N_STEP(8, 9);  N_STEP(9, 0);

#undef N_STEP
#undef N_ALOAD
#undef N_STAGE

#pragma unroll
    for (int f = 0; f < 2; ++f) {
        const int col = y * 32 + f * 16 + lane16;
        const bool valid = col < MEM;
        float bff = 0, bi = 0, bo = 0, bu = 0;
        if (valid) {
            bff = b_fioux[col]; bi = b_fioux[300 + col];
            bo = b_fioux[600 + col]; bu = b_fioux[900 + col];
        }
#pragma unroll
        for (int mi = 0; mi < 2; ++mi)
#pragma unroll
            for (int r = 0; r < 4; ++r) {
                int row = w * 32 + mi * 16 + quad * 4 + r;
                size_t hIdx = ((size_t)node * BATCH + row) * NP + col;
                if (valid) {
                    float cl = (float)C[((size_t)li * BATCH + row) * MEM + col];
                    float cr = (float)C[((size_t)ri * BATCH + row) * MEM + col];
                    float ig = sigf(acc[0][f][mi][r] + bi);
                    float og = sigf(acc[1][f][mi][r] + bo);
                    float ug = tanhf_(acc[2][f][mi][r] + bu);
                    float fl = sigf(acc[3][f][mi][r] + bff);
                    float fr = sigf(acc[4][f][mi][r] + bff);
                    float c = ig * ug + fl * cl + fr * cr;
                    float h = og * tanhf_(c);
                    C[((size_t)node * BATCH + row) * MEM + col] = (half_t)c;
                    H[hIdx] = f2bf(h);
                    if (out) {
                        out[row * MEM + col] = c;
                        out[OUT_HALF + row * MEM + col] = h;
                    }
                } else {
                    H[hIdx] = 0;
                }
            }
    }
}

extern "C" void kernel_launch(void* const* d_in, const int* in_sizes, int n_in,
                              void* d_out, int out_size, void* d_ws, size_t ws_size,
                              hipStream_t stream) {
    const float* inputs  = (const float*)d_in[0];
    const float* Wfioux  = (const float*)d_in[1];
    const float* b_fioux = (const float*)d_in[2];
    const float* Wiouh   = (const float*)d_in[3];
    const float* Wfh     = (const float*)d_in[4];
    const int*   left_idx  = (const int*)d_in[5];
    const int*   right_idx = (const int*)d_in[6];

    half_t* C   = (half_t*)d_ws;                              // [1023][128][300] fp16
    short*  H   = (short*)(C + (size_t)NODES * BATCH * MEM);  // [1023][128][320] bf16
    short* WpkN = H + (size_t)NODES * BATCH * NP;             // 2000 frag-blocks
    short* WpkL = WpkN + (size_t)2000 * 512;                  // 600 frag-blocks
    short* X    = WpkL + (size_t)600 * 512;                   // [512][128][320] bf16
    float* out  = (float*)d_out;

    pack_x<<<(LEAVES * BATCH * (NP / 4) + 255) / 256, 256, 0, stream>>>(inputs, X);
    pack_leaf_w<<<150, 256, 0, stream>>>(Wfioux, WpkL);
    pack_node_w<<<500, 256, 0, stream>>>(Wiouh, Wfh, WpkN);

    leaf_mfma<<<LEAVES * 5, 256, 0, stream>>>(X, WpkL, b_fioux, C, H);

    static const int starts[9] = {512, 768, 896, 960, 992, 1008, 1016, 1020, 1022};
    static const int sizes [9] = {256, 128,  64,  32,  16,    8,    4,    2,    1};
    for (int lvl = 0; lvl < 9; ++lvl) {
        bool root = (lvl == 8);
        node_mfma<<<sizes[lvl] * 10, 256, 0, stream>>>(
            WpkN, b_fioux, left_idx, right_idx, C, H, starts[lvl], sizes[lvl],
            root ? out : nullptr);
    }
}